// Round 2
// baseline (384.864 us; speedup 1.0000x reference)
//
#include <hip/hip_runtime.h>
#include <hip/hip_bf16.h>
#include <hip/hip_cooperative_groups.h>

namespace cg = cooperative_groups;

typedef __attribute__((ext_vector_type(8))) short short8;
typedef __attribute__((ext_vector_type(4))) float floatx4;
typedef __attribute__((ext_vector_type(4))) unsigned int uintx4;

// fast GELU: x * (1 - 1/(exp(2u)+1)), u = 0.79788456*(x + 0.044715 x^3)
__device__ __forceinline__ float gelu_fast(float x)
{
    float u = 0.7978845608f * x * (1.0f + 0.044715f * x * x);
    float e = __builtin_amdgcn_exp2f(2.885390082f * u);   // exp(2u)
    return x - x * __builtin_amdgcn_rcpf(e + 1.0f);
}

__device__ __forceinline__ int wave_incl_scan(int v, int lane)
{
#pragma unroll
    for (int o = 1; o < 64; o <<= 1) {
        int u = __shfl_up(v, o);
        if (lane >= o) v += u;
    }
    return v;
}

// One cooperative kernel replacing memset+prep+scan+scan+scatter:
//  A: zero cnt, convert W to fragment-ordered bf16 (frag f=ko*8+nt, lane l:
//     8 elems W[ko*32+quad*8+j][nt*16+col])
//  B: count triangles per dst (slot = per-dst arrival index)
//  C1: per-1024-chunk exclusive scan of cnt -> excl, chunk totals -> partial
//  C2: block 0 scans partial -> pscan
//  D: scatter records {i0*256,i1*256} into dst-sorted srec; rowinfo={start,cnt}
__global__ __launch_bounds__(1024)
void prep_all(const float* __restrict__ Wg, uintx4* __restrict__ wq,
              const int* __restrict__ tri, int* __restrict__ cnt,
              int* __restrict__ slot, int* __restrict__ excl,
              int* __restrict__ partial, int* __restrict__ pscan,
              int2* __restrict__ srec, int2* __restrict__ rowinfo,
              int E, int T)
{
    __shared__ int ws[16];
    cg::grid_group grid = cg::this_grid();
    const int tid  = threadIdx.x;
    const int g    = blockIdx.x * 1024 + tid;
    const int nthr = gridDim.x * 1024;
    const int lane = tid & 63, wv = tid >> 6;

    // ---- Phase A ----
    for (int i = g; i < E; i += nthr) cnt[i] = 0;
    for (int i = g; i < 6144; i += nthr) {
        int frag = i >> 6, l = i & 63;
        int ko = frag >> 3, nt = frag & 7;
        int col = l & 15, quad = l >> 4;
        unsigned short tmp[8] __attribute__((aligned(16)));
#pragma unroll
        for (int j = 0; j < 8; ++j) {
            __hip_bfloat16 b =
                __float2bfloat16(Wg[(ko * 32 + quad * 8 + j) * 128 + nt * 16 + col]);
            tmp[j] = *(unsigned short*)&b;
        }
        wq[i] = *(const uintx4*)tmp;
    }
    grid.sync();

    // ---- Phase B ----
    for (int i = g; i < T; i += nthr) {
        int i2 = tri[i * 3 + 2];
        slot[i] = atomicAdd(&cnt[i2], 1);
    }
    grid.sync();

    // ---- Phase C1 ----
    int nchunks = (E + 1023) >> 10;
    for (int ch = blockIdx.x; ch < nchunks; ch += gridDim.x) {
        int e = ch * 1024 + tid;
        int v = (e < E) ? cnt[e] : 0;
        int sc = wave_incl_scan(v, lane);
        if (lane == 63) ws[wv] = sc;
        __syncthreads();
        if (wv == 0) {
            int b = (lane < 16) ? ws[lane] : 0;
            int bs = wave_incl_scan(b, lane);
            if (lane < 16) ws[lane] = bs;
        }
        __syncthreads();
        int off = wv ? ws[wv - 1] : 0;
        if (e < E) excl[e] = off + sc - v;
        if (tid == 0) partial[ch] = ws[15];
        __syncthreads();
    }
    grid.sync();

    // ---- Phase C2 ----
    if (blockIdx.x == 0) {
        int v = (tid < nchunks) ? partial[tid] : 0;
        int sc = wave_incl_scan(v, lane);
        if (lane == 63) ws[wv] = sc;
        __syncthreads();
        if (wv == 0) {
            int b = (lane < 16) ? ws[lane] : 0;
            int bs = wave_incl_scan(b, lane);
            if (lane < 16) ws[lane] = bs;
        }
        __syncthreads();
        int off = wv ? ws[wv - 1] : 0;
        if (tid < nchunks) pscan[tid] = off + sc - v;
    }
    grid.sync();

    // ---- Phase D ----
    for (int i = g; i < T; i += nthr) {
        int i0 = tri[i * 3 + 0];
        int i1 = tri[i * 3 + 1];
        int i2 = tri[i * 3 + 2];
        int pos = excl[i2] + pscan[i2 >> 10] + slot[i];
        srec[pos] = make_int2(i0 << 8, i1 << 8);   // byte offsets into G rows
    }
    for (int i = g; i < E; i += nthr)
        rowinfo[i] = make_int2(excl[i] + pscan[i >> 10], cnt[i]);
}

// One-pass dense GEMM: all 3 W slices resident in 96KB LDS; A tile loaded and
// converted once, used for r=0,1,2. Output bf16, permuted C-layout (row i:
// physical elem col*8+nt = logical col nt*16+col). No barriers in main loop.
__global__ __launch_bounds__(1024, 1)
void edge_gemm(const float* __restrict__ fe_f, const uintx4* __restrict__ wq,
               unsigned short* __restrict__ G, int E)
{
    __shared__ uintx4 ldsW[6144];   // 96 KB: 12 global-ko x 8 nt fragment blocks

    const int tid  = threadIdx.x;
    const int wv   = tid >> 6;
    const int lane = tid & 63;
    const int col  = lane & 15;
    const int quad = lane >> 4;
    const int ntiles = (E + 15) >> 4;

    for (int i = tid; i < 6144; i += 1024) ldsW[i] = wq[i];
    __syncthreads();

#pragma unroll 1
    for (int tile = blockIdx.x * 16 + wv; tile < ntiles; tile += gridDim.x * 16) {
        int row_a = tile * 16 + col;
        if (row_a >= E) row_a = E - 1;
        const float* arow = fe_f + (size_t)row_a * 128 + quad * 8;

        floatx4 f[8];
#pragma unroll
        for (int l = 0; l < 8; ++l)
            f[l] = *(const floatx4*)(arow + (l >> 1) * 32 + (l & 1) * 4);

        short8 a[4];
#pragma unroll
        for (int ko = 0; ko < 4; ++ko) {
            unsigned short tmp[8] __attribute__((aligned(16)));
#pragma unroll
            for (int j = 0; j < 8; ++j) {
                __hip_bfloat16 b = __float2bfloat16(f[ko * 2 + (j >> 2)][j & 3]);
                tmp[j] = *(unsigned short*)&b;
            }
            a[ko] = *(const short8*)tmp;
        }

#pragma unroll 1
        for (int r = 0; r < 3; ++r) {
            floatx4 acc[8];
#pragma unroll
            for (int nt = 0; nt < 8; ++nt) acc[nt] = (floatx4)0.0f;

#pragma unroll
            for (int ko = 0; ko < 4; ++ko) {
#pragma unroll
                for (int nt = 0; nt < 8; ++nt) {
                    short8 bf = *(const short8*)&ldsW[r * 2048 + (ko * 8 + nt) * 64 + lane];
                    acc[nt] = __builtin_amdgcn_mfma_f32_16x16x32_bf16(a[ko], bf, acc[nt], 0, 0, 0);
                }
            }

            unsigned short* Gr = G + (size_t)r * E * 128;
#pragma unroll
            for (int rr = 0; rr < 4; ++rr) {
                int row = tile * 16 + quad * 4 + rr;
                if (row < E) {
                    unsigned short pk[8] __attribute__((aligned(16)));
#pragma unroll
                    for (int nt = 0; nt < 8; ++nt) {
                        __hip_bfloat16 hb = __float2bfloat16(acc[nt][rr]);
                        pk[nt] = *(unsigned short*)&hb;
                    }
                    *(uintx4*)(Gr + (size_t)row * 128 + col * 8) = *(const uintx4*)pk;
                }
            }
        }
    }
}

// Per-edge fused gather + GELU + mean + LayerNorm, CSR + batched-pipeline.
// One wave per edge row. Records loaded 64-wide once; inner loop processes
// 8 triangles per batch: 8 uniform-lane shfl broadcasts (v_readlane), 16
// gathers issued back-to-back (one vmcnt wait per batch), then 8x compute.
// Lane (col,q) covers logical cols j0=32q+col, j1=j0+16 (permuted layout).
__global__ __launch_bounds__(256)
void mean_ln(const unsigned short* __restrict__ G, const int2* __restrict__ rowinfo,
             const int2* __restrict__ srec, const float* __restrict__ bias,
             const float* __restrict__ gamma, const float* __restrict__ beta,
             float* __restrict__ out, int E)
{
    int lane = threadIdx.x & 63;
    int row  = blockIdx.x * 4 + (threadIdx.x >> 6);
    if (row >= E) return;
    int col = lane & 15, q = lane >> 4;
    int boff = (col << 4) + (q << 2);   // byte offset within 256B row
    const char* g0 = (const char*)G + boff;
    const char* g1 = g0 + (size_t)E * 256;
    const char* g2 = g1 + (size_t)E * 256;
    int j0 = q * 32 + col, j1 = j0 + 16;

    int2 ri = rowinfo[row];
    int s = ri.x, c = ri.y;

    unsigned int w2 = *(const unsigned int*)(g2 + (size_t)row * 256);
    float base0 = __uint_as_float(w2 << 16) + bias[j0];
    float base1 = __uint_as_float(w2 & 0xffff0000u) + bias[j1];

    float x0 = 0.0f, x1 = 0.0f;
    for (int p0 = 0; p0 < c; p0 += 64) {
        int nav = min(64, c - p0);
        int2 rr = srec[s + p0 + (lane < nav ? lane : 0)];
        for (int p = 0; p < nav; p += 8) {
            int n8 = min(8, nav - p);
            unsigned int w0[8], w1[8];
#pragma unroll
            for (int j = 0; j < 8; ++j) {
                int kk = p + (j < n8 ? j : 0);
                int o0 = __shfl(rr.x, kk);
                int o1 = __shfl(rr.y, kk);
                w0[j] = *(const unsigned int*)(g0 + (size_t)(unsigned)o0);
                w1[j] = *(const unsigned int*)(g1 + (size_t)(unsigned)o1);
            }
#pragma unroll
            for (int j = 0; j < 8; ++j) {
                if (j < n8) {
                    float s0 = __uint_as_float(w0[j] << 16)
                             + __uint_as_float(w1[j] << 16) + base0;
                    float s1 = __uint_as_float(w0[j] & 0xffff0000u)
                             + __uint_as_float(w1[j] & 0xffff0000u) + base1;
                    x0 += gelu_fast(s0);
                    x1 += gelu_fast(s1);
                }
            }
        }
    }

    float inv = 1.0f / fmaxf((float)c, 1.0f);
    float m0 = x0 * inv, m1 = x1 * inv;
    float sm = m0 + m1;
#pragma unroll
    for (int o = 32; o > 0; o >>= 1) sm += __shfl_xor(sm, o);
    float mu = sm * (1.0f / 128.0f);
    float d0 = m0 - mu, d1 = m1 - mu;
    float v = d0 * d0 + d1 * d1;
#pragma unroll
    for (int o = 32; o > 0; o >>= 1) v += __shfl_xor(v, o);
    float rstd = rsqrtf(v * (1.0f / 128.0f) + 1e-5f);
    out[(size_t)row * 128 + j0] = d0 * rstd * gamma[j0] + beta[j0];
    out[(size_t)row * 128 + j1] = d1 * rstd * gamma[j1] + beta[j1];
}

extern "C" void kernel_launch(void* const* d_in, const int* in_sizes, int n_in,
                              void* d_out, int out_size, void* d_ws, size_t ws_size,
                              hipStream_t stream)
{
    const float* fe_f  = (const float*)d_in[0];
    const float* Wg    = (const float*)d_in[1];
    const float* bias  = (const float*)d_in[2];
    const float* gamma = (const float*)d_in[3];
    const float* beta  = (const float*)d_in[4];
    const int*   tri   = (const int*)d_in[5];

    int E = in_sizes[0] / 128;
    int T = in_sizes[5] / 3;

    // ws: G (3*E*128 bf16) | srec (T int2) | wq (96KB) | slot (T i32) |
    //     cnt (E) | excl (E) | partial (1024) | pscan (1024) | rowinfo (E int2)
    unsigned short* G = (unsigned short*)d_ws;
    int2* srec = (int2*)((char*)d_ws + (size_t)3 * E * 256);
    uintx4* wq = (uintx4*)(srec + T);
    int* slot = (int*)(wq + 6144);
    int* cnt  = slot + T;
    int* excl = cnt + E;
    int* partial = excl + E;
    int* pscan = partial + 1024;
    int2* rowinfo = (int2*)(pscan + 1024);

    void* cargs[] = { (void*)&Wg, (void*)&wq, (void*)&tri, (void*)&cnt,
                      (void*)&slot, (void*)&excl, (void*)&partial, (void*)&pscan,
                      (void*)&srec, (void*)&rowinfo, (void*)&E, (void*)&T };
    hipLaunchCooperativeKernel((const void*)prep_all, dim3(256), dim3(1024),
                               cargs, 0, stream);

    edge_gemm<<<256, 1024, 0, stream>>>(fe_f, wq, G, E);

    mean_ln<<<(E + 3) / 4, 256, 0, stream>>>(G, rowinfo, srec, bias, gamma, beta,
                                             (float*)d_out, E);
}

// Round 3
// 278.924 us; speedup vs baseline: 1.3798x; 1.3798x over previous
//
#include <hip/hip_runtime.h>
#include <hip/hip_bf16.h>

typedef __attribute__((ext_vector_type(8))) short short8;
typedef __attribute__((ext_vector_type(4))) float floatx4;
typedef __attribute__((ext_vector_type(4))) unsigned int uintx4;

// fast GELU: x * (1 - 1/(exp(2u)+1)), u = 0.79788456*(x + 0.044715 x^3)
__device__ __forceinline__ float gelu_fast(float x)
{
    float u = 0.7978845608f * x * (1.0f + 0.044715f * x * x);
    float e = __builtin_amdgcn_exp2f(2.885390082f * u);   // exp(2u)
    return x - x * __builtin_amdgcn_rcpf(e + 1.0f);
}

// prep: [0,T): count triangles per dst, record slot; [T,T+6144): fragment-
// ordered bf16 W (frag f=ko*8+nt over global ko 0..11, lane l: 8 elems
// W[ko*32+quad*8+j][nt*16+col]).
__global__ __launch_bounds__(256)
void prep(const float* __restrict__ Wg, uintx4* __restrict__ wq,
          const int* __restrict__ tri, int* __restrict__ cnt,
          int* __restrict__ slot, int T)
{
    int g = blockIdx.x * 256 + threadIdx.x;
    if (g < T) {
        int i2 = tri[g * 3 + 2];
        slot[g] = atomicAdd(&cnt[i2], 1);
    } else {
        int i = g - T;
        if (i < 6144) {
            int frag = i >> 6, lane = i & 63;
            int ko = frag >> 3, nt = frag & 7;
            int col = lane & 15, quad = lane >> 4;
            unsigned short tmp[8] __attribute__((aligned(16)));
#pragma unroll
            for (int j = 0; j < 8; ++j) {
                __hip_bfloat16 b =
                    __float2bfloat16(Wg[(ko * 32 + quad * 8 + j) * 128 + nt * 16 + col]);
                tmp[j] = *(unsigned short*)&b;
            }
            wq[i] = *(const uintx4*)tmp;
        }
    }
}

__device__ __forceinline__ int wave_incl_scan(int v, int lane)
{
#pragma unroll
    for (int o = 1; o < 64; o <<= 1) {
        int u = __shfl_up(v, o);
        if (lane >= o) v += u;
    }
    return v;
}

// Block-level exclusive scan of 1024 elements; writes per-element exclusive
// prefix (within block) and block total to partial[] (if non-null).
__global__ __launch_bounds__(1024)
void scan_blk(const int* __restrict__ in, int* __restrict__ outExcl,
              int* __restrict__ partial, int n)
{
    __shared__ int ws[16];
    int t = threadIdx.x;
    int g = blockIdx.x * 1024 + t;
    int lane = t & 63, wv = t >> 6;
    int v = (g < n) ? in[g] : 0;
    int sc = wave_incl_scan(v, lane);
    if (lane == 63) ws[wv] = sc;
    __syncthreads();
    if (wv == 0) {
        int b = (lane < 16) ? ws[lane] : 0;
        int bs = wave_incl_scan(b, lane);
        if (lane < 16) ws[lane] = bs;
    }
    __syncthreads();
    int off = wv ? ws[wv - 1] : 0;
    if (g < n) outExcl[g] = off + sc - v;
    if (partial && t == 0) partial[blockIdx.x] = ws[15];
}

// Scatter triangles into dst-sorted order (pre-scaled byte offsets); also emit
// rowinfo = {start, cnt} per edge and zero-pad srec[T..T+7] for batched loads.
__global__ __launch_bounds__(256)
void scatter(const int* __restrict__ tri, const int* __restrict__ slot,
             const int* __restrict__ excl, const int* __restrict__ pscan,
             const int* __restrict__ cnt, int2* __restrict__ srec,
             int2* __restrict__ rowinfo, int E, int T)
{
    int g = blockIdx.x * 256 + threadIdx.x;
    if (g < T) {
        int i0 = tri[g * 3 + 0];
        int i1 = tri[g * 3 + 1];
        int i2 = tri[g * 3 + 2];
        int pos = excl[i2] + pscan[i2 >> 10] + slot[g];
        srec[pos] = make_int2(i0 << 8, i1 << 8);   // byte offsets into G rows
    }
    if (g < E)
        rowinfo[g] = make_int2(excl[g] + pscan[g >> 10], cnt[g]);
    if (g < 8)
        srec[T + g] = make_int2(0, 0);
}

// One-pass dense GEMM: all 3 W slices resident in 96KB LDS; A tile loaded and
// converted once, used for r=0,1,2. Output bf16, permuted C-layout (row i:
// physical elem col*8+nt = logical col nt*16+col). No barriers in main loop.
__global__ __launch_bounds__(1024, 1)
void edge_gemm(const float* __restrict__ fe_f, const uintx4* __restrict__ wq,
               unsigned short* __restrict__ G, int E)
{
    __shared__ uintx4 ldsW[6144];   // 96 KB: 12 global-ko x 8 nt fragment blocks

    const int tid  = threadIdx.x;
    const int wv   = tid >> 6;
    const int lane = tid & 63;
    const int col  = lane & 15;
    const int quad = lane >> 4;
    const int ntiles = (E + 15) >> 4;

    for (int i = tid; i < 6144; i += 1024) ldsW[i] = wq[i];
    __syncthreads();

#pragma unroll 1
    for (int tile = blockIdx.x * 16 + wv; tile < ntiles; tile += gridDim.x * 16) {
        int row_a = tile * 16 + col;
        if (row_a >= E) row_a = E - 1;
        const float* arow = fe_f + (size_t)row_a * 128 + quad * 8;

        floatx4 f[8];
#pragma unroll
        for (int l = 0; l < 8; ++l)
            f[l] = *(const floatx4*)(arow + (l >> 1) * 32 + (l & 1) * 4);

        short8 a[4];
#pragma unroll
        for (int ko = 0; ko < 4; ++ko) {
            unsigned short tmp[8] __attribute__((aligned(16)));
#pragma unroll
            for (int j = 0; j < 8; ++j) {
                __hip_bfloat16 b = __float2bfloat16(f[ko * 2 + (j >> 2)][j & 3]);
                tmp[j] = *(unsigned short*)&b;
            }
            a[ko] = *(const short8*)tmp;
        }

#pragma unroll 1
        for (int r = 0; r < 3; ++r) {
            floatx4 acc[8];
#pragma unroll
            for (int nt = 0; nt < 8; ++nt) acc[nt] = (floatx4)0.0f;

#pragma unroll
            for (int ko = 0; ko < 4; ++ko) {
#pragma unroll
                for (int nt = 0; nt < 8; ++nt) {
                    short8 bf = *(const short8*)&ldsW[r * 2048 + (ko * 8 + nt) * 64 + lane];
                    acc[nt] = __builtin_amdgcn_mfma_f32_16x16x32_bf16(a[ko], bf, acc[nt], 0, 0, 0);
                }
            }

            unsigned short* Gr = G + (size_t)r * E * 128;
#pragma unroll
            for (int rr = 0; rr < 4; ++rr) {
                int row = tile * 16 + quad * 4 + rr;
                if (row < E) {
                    unsigned short pk[8] __attribute__((aligned(16)));
#pragma unroll
                    for (int nt = 0; nt < 8; ++nt) {
                        __hip_bfloat16 hb = __float2bfloat16(acc[nt][rr]);
                        pk[nt] = *(unsigned short*)&hb;
                    }
                    *(uintx4*)(Gr + (size_t)row * 128 + col * 8) = *(const uintx4*)pk;
                }
            }
        }
    }
}

// Per-edge fused gather + GELU + mean + LayerNorm, CSR + uniform batched loads.
// One wave per edge row. Chain depth per row is 3 memory levels for c<=8
// (rowinfo -> 8x srec broadcast loads -> 16 gathers), vs ~5+c before. Steps
// past c are clamped to record c-1 and predicated out of the sum (order of
// valid-term summation unchanged). Lane (col,q) covers logical cols
// j0=32q+col, j1=j0+16 (permuted layout).
__global__ __launch_bounds__(256)
void mean_ln(const unsigned short* __restrict__ G, const int2* __restrict__ rowinfo,
             const int2* __restrict__ srec, const float* __restrict__ bias,
             const float* __restrict__ gamma, const float* __restrict__ beta,
             float* __restrict__ out, int E)
{
    int lane = threadIdx.x & 63;
    int row  = blockIdx.x * 4 + (threadIdx.x >> 6);
    if (row >= E) return;
    int col = lane & 15, q = lane >> 4;
    int boff = (col << 4) + (q << 2);   // byte offset within 256B row
    const char* g0 = (const char*)G + boff;
    const char* g1 = g0 + (size_t)E * 256;
    const char* g2 = g1 + (size_t)E * 256;
    int j0 = q * 32 + col, j1 = j0 + 16;

    int2 ri = rowinfo[row];
    int s = ri.x, c = ri.y;

    unsigned int w2 = *(const unsigned int*)(g2 + (size_t)row * 256);
    float base0 = __uint_as_float(w2 << 16) + bias[j0];
    float base1 = __uint_as_float(w2 & 0xffff0000u) + bias[j1];

    float x0 = 0.0f, x1 = 0.0f;
    for (int p = 0; p < c; p += 8) {
        unsigned int o0[8], o1[8];
#pragma unroll
        for (int j = 0; j < 8; ++j) {
            int k = p + j;
            int kc = (k < c) ? k : (c - 1);
            int2 r = srec[s + kc];          // lane-uniform addr -> 1 request
            o0[j] = (unsigned)r.x;
            o1[j] = (unsigned)r.y;
        }
        unsigned int w0[8], w1[8];
#pragma unroll
        for (int j = 0; j < 8; ++j) {
            w0[j] = *(const unsigned int*)(g0 + (size_t)o0[j]);
            w1[j] = *(const unsigned int*)(g1 + (size_t)o1[j]);
        }
#pragma unroll
        for (int j = 0; j < 8; ++j) {
            bool ok = (p + j) < c;
            float s0 = __uint_as_float(w0[j] << 16)
                     + __uint_as_float(w1[j] << 16) + base0;
            float s1 = __uint_as_float(w0[j] & 0xffff0000u)
                     + __uint_as_float(w1[j] & 0xffff0000u) + base1;
            x0 += ok ? gelu_fast(s0) : 0.0f;
            x1 += ok ? gelu_fast(s1) : 0.0f;
        }
    }

    float gm0 = gamma[j0], gm1 = gamma[j1];
    float bt0 = beta[j0],  bt1 = beta[j1];

    float inv = 1.0f / fmaxf((float)c, 1.0f);
    float m0 = x0 * inv, m1 = x1 * inv;
    float sm = m0 + m1;
#pragma unroll
    for (int o = 32; o > 0; o >>= 1) sm += __shfl_xor(sm, o);
    float mu = sm * (1.0f / 128.0f);
    float d0 = m0 - mu, d1 = m1 - mu;
    float v = d0 * d0 + d1 * d1;
#pragma unroll
    for (int o = 32; o > 0; o >>= 1) v += __shfl_xor(v, o);
    float rstd = rsqrtf(v * (1.0f / 128.0f) + 1e-5f);
    out[(size_t)row * 128 + j0] = d0 * rstd * gm0 + bt0;
    out[(size_t)row * 128 + j1] = d1 * rstd * gm1 + bt1;
}

extern "C" void kernel_launch(void* const* d_in, const int* in_sizes, int n_in,
                              void* d_out, int out_size, void* d_ws, size_t ws_size,
                              hipStream_t stream)
{
    const float* fe_f  = (const float*)d_in[0];
    const float* Wg    = (const float*)d_in[1];
    const float* bias  = (const float*)d_in[2];
    const float* gamma = (const float*)d_in[3];
    const float* beta  = (const float*)d_in[4];
    const int*   tri   = (const int*)d_in[5];

    int E = in_sizes[0] / 128;
    int T = in_sizes[5] / 3;

    // ws: G (3*E*128 bf16) | srec (T+8 int2) | wq (96KB) | slot (T i32) |
    //     cnt (E) | excl (E) | partial (1024) | pscan (1024) | rowinfo (E int2)
    unsigned short* G = (unsigned short*)d_ws;
    int2* srec = (int2*)((char*)d_ws + (size_t)3 * E * 256);
    uintx4* wq = (uintx4*)(srec + T + 8);
    int* slot = (int*)(wq + 6144);
    int* cnt  = slot + T;
    int* excl = cnt + E;
    int* partial = excl + E;
    int* pscan = partial + 1024;
    int2* rowinfo = (int2*)(pscan + 1024);

    hipMemsetAsync(cnt, 0, (size_t)E * sizeof(int), stream);

    int total = T + 6144;
    prep<<<(total + 255) / 256, 256, 0, stream>>>(Wg, wq, tri, cnt, slot, T);

    int NB = (E + 1023) / 1024;   // 98 for E=100000 (must be <= 1024)
    scan_blk<<<NB, 1024, 0, stream>>>(cnt, excl, partial, E);
    scan_blk<<<1, 1024, 0, stream>>>(partial, pscan, nullptr, NB);

    scatter<<<(T + 255) / 256, 256, 0, stream>>>(tri, slot, excl, pscan, cnt,
                                                 srec, rowinfo, E, T);

    edge_gemm<<<256, 1024, 0, stream>>>(fe_f, wq, G, E);

    mean_ln<<<(E + 3) / 4, 256, 0, stream>>>(G, rowinfo, srec, bias, gamma, beta,
                                             (float*)d_out, E);
}

// Round 4
// 233.480 us; speedup vs baseline: 1.6484x; 1.1946x over previous
//
#include <hip/hip_runtime.h>
#include <hip/hip_bf16.h>

typedef __attribute__((ext_vector_type(8))) short short8;
typedef __attribute__((ext_vector_type(4))) float floatx4;
typedef __attribute__((ext_vector_type(4))) unsigned int uintx4;

// fast GELU: x * (1 - 1/(exp(2u)+1)), u = 0.79788456*(x + 0.044715 x^3)
__device__ __forceinline__ float gelu_fast(float x)
{
    float u = 0.7978845608f * x * (1.0f + 0.044715f * x * x);
    float e = __builtin_amdgcn_exp2f(2.885390082f * u);   // exp(2u)
    return x - x * __builtin_amdgcn_rcpf(e + 1.0f);
}

// prep: [0,T): count triangles per dst, record slot; [T,T+6144): fragment-
// ordered bf16 W (frag f=ko*8+nt over global ko 0..11, lane l: 8 elems
// W[ko*32+quad*8+j][nt*16+col]).
__global__ __launch_bounds__(256)
void prep(const float* __restrict__ Wg, uintx4* __restrict__ wq,
          const int* __restrict__ tri, int* __restrict__ cnt,
          int* __restrict__ slot, int T)
{
    int g = blockIdx.x * 256 + threadIdx.x;
    if (g < T) {
        int i2 = tri[g * 3 + 2];
        slot[g] = atomicAdd(&cnt[i2], 1);
    } else {
        int i = g - T;
        if (i < 6144) {
            int frag = i >> 6, lane = i & 63;
            int ko = frag >> 3, nt = frag & 7;
            int col = lane & 15, quad = lane >> 4;
            unsigned short tmp[8] __attribute__((aligned(16)));
#pragma unroll
            for (int j = 0; j < 8; ++j) {
                __hip_bfloat16 b =
                    __float2bfloat16(Wg[(ko * 32 + quad * 8 + j) * 128 + nt * 16 + col]);
                tmp[j] = *(unsigned short*)&b;
            }
            wq[i] = *(const uintx4*)tmp;
        }
    }
}

__device__ __forceinline__ int wave_incl_scan(int v, int lane)
{
#pragma unroll
    for (int o = 1; o < 64; o <<= 1) {
        int u = __shfl_up(v, o);
        if (lane >= o) v += u;
    }
    return v;
}

// Block-level exclusive scan of 1024 elements; writes per-element exclusive
// prefix (within block) and block total to partial[] (if non-null).
__global__ __launch_bounds__(1024)
void scan_blk(const int* __restrict__ in, int* __restrict__ outExcl,
              int* __restrict__ partial, int n)
{
    __shared__ int ws[16];
    int t = threadIdx.x;
    int g = blockIdx.x * 1024 + t;
    int lane = t & 63, wv = t >> 6;
    int v = (g < n) ? in[g] : 0;
    int sc = wave_incl_scan(v, lane);
    if (lane == 63) ws[wv] = sc;
    __syncthreads();
    if (wv == 0) {
        int b = (lane < 16) ? ws[lane] : 0;
        int bs = wave_incl_scan(b, lane);
        if (lane < 16) ws[lane] = bs;
    }
    __syncthreads();
    int off = wv ? ws[wv - 1] : 0;
    if (g < n) outExcl[g] = off + sc - v;
    if (partial && t == 0) partial[blockIdx.x] = ws[15];
}

// Scatter triangles into dst-sorted order (pre-scaled byte offsets); also emit
// rowinfo = {start, cnt} per edge.
__global__ __launch_bounds__(256)
void scatter(const int* __restrict__ tri, const int* __restrict__ slot,
             const int* __restrict__ excl, const int* __restrict__ pscan,
             const int* __restrict__ cnt, int2* __restrict__ srec,
             int2* __restrict__ rowinfo, int E, int T)
{
    int g = blockIdx.x * 256 + threadIdx.x;
    if (g < T) {
        int i0 = tri[g * 3 + 0];
        int i1 = tri[g * 3 + 1];
        int i2 = tri[g * 3 + 2];
        int pos = excl[i2] + pscan[i2 >> 10] + slot[g];
        srec[pos] = make_int2(i0 << 8, i1 << 8);   // byte offsets into G rows
    }
    if (g < E)
        rowinfo[g] = make_int2(excl[g] + pscan[g >> 10], cnt[g]);
}

// One-pass dense GEMM: all 3 W slices resident in 96KB LDS; A tile loaded and
// converted once, used for r=0,1,2. Output bf16, permuted C-layout (row i:
// physical elem col*8+nt = logical col nt*16+col). No barriers in main loop.
__global__ __launch_bounds__(1024, 1)
void edge_gemm(const float* __restrict__ fe_f, const uintx4* __restrict__ wq,
               unsigned short* __restrict__ G, int E)
{
    __shared__ uintx4 ldsW[6144];   // 96 KB: 12 global-ko x 8 nt fragment blocks

    const int tid  = threadIdx.x;
    const int wv   = tid >> 6;
    const int lane = tid & 63;
    const int col  = lane & 15;
    const int quad = lane >> 4;
    const int ntiles = (E + 15) >> 4;

    for (int i = tid; i < 6144; i += 1024) ldsW[i] = wq[i];
    __syncthreads();

#pragma unroll 1
    for (int tile = blockIdx.x * 16 + wv; tile < ntiles; tile += gridDim.x * 16) {
        int row_a = tile * 16 + col;
        if (row_a >= E) row_a = E - 1;
        const float* arow = fe_f + (size_t)row_a * 128 + quad * 8;

        floatx4 f[8];
#pragma unroll
        for (int l = 0; l < 8; ++l)
            f[l] = *(const floatx4*)(arow + (l >> 1) * 32 + (l & 1) * 4);

        short8 a[4];
#pragma unroll
        for (int ko = 0; ko < 4; ++ko) {
            unsigned short tmp[8] __attribute__((aligned(16)));
#pragma unroll
            for (int j = 0; j < 8; ++j) {
                __hip_bfloat16 b = __float2bfloat16(f[ko * 2 + (j >> 2)][j & 3]);
                tmp[j] = *(unsigned short*)&b;
            }
            a[ko] = *(const short8*)tmp;
        }

#pragma unroll 1
        for (int r = 0; r < 3; ++r) {
            floatx4 acc[8];
#pragma unroll
            for (int nt = 0; nt < 8; ++nt) acc[nt] = (floatx4)0.0f;

#pragma unroll
            for (int ko = 0; ko < 4; ++ko) {
#pragma unroll
                for (int nt = 0; nt < 8; ++nt) {
                    short8 bf = *(const short8*)&ldsW[r * 2048 + (ko * 8 + nt) * 64 + lane];
                    acc[nt] = __builtin_amdgcn_mfma_f32_16x16x32_bf16(a[ko], bf, acc[nt], 0, 0, 0);
                }
            }

            unsigned short* Gr = G + (size_t)r * E * 128;
#pragma unroll
            for (int rr = 0; rr < 4; ++rr) {
                int row = tile * 16 + quad * 4 + rr;
                if (row < E) {
                    unsigned short pk[8] __attribute__((aligned(16)));
#pragma unroll
                    for (int nt = 0; nt < 8; ++nt) {
                        __hip_bfloat16 hb = __float2bfloat16(acc[nt][rr]);
                        pk[nt] = *(unsigned short*)&hb;
                    }
                    *(uintx4*)(Gr + (size_t)row * 128 + col * 8) = *(const uintx4*)pk;
                }
            }
        }
    }
}

// Per-edge fused gather + GELU + mean + LayerNorm, CSR version (round-1 inner
// loop: one coalesced 64-wide record load + bpermute broadcasts keeps record
// distribution OFF the VMEM queue). rowinfo gives a 1-load prologue. Since c
// is wave-uniform, rows with remainder <= 4 use a half-size batch body to cut
// GELU padding waste (~34% of loop VALU at cbar=4).
// Lane (col,q) covers logical cols j0=32q+col, j1=j0+16 (permuted layout).
__global__ __launch_bounds__(256)
void mean_ln(const unsigned short* __restrict__ G, const int2* __restrict__ rowinfo,
             const int2* __restrict__ srec, const float* __restrict__ bias,
             const float* __restrict__ gamma, const float* __restrict__ beta,
             float* __restrict__ out, int E)
{
    int lane = threadIdx.x & 63;
    int row  = blockIdx.x * 4 + (threadIdx.x >> 6);
    if (row >= E) return;
    int col = lane & 15, q = lane >> 4;
    int boff = (col << 4) + (q << 2);   // byte offset within 256B row
    const char* g0 = (const char*)G + boff;
    const char* g1 = g0 + (size_t)E * 256;
    const char* g2 = g1 + (size_t)E * 256;
    int j0 = q * 32 + col, j1 = j0 + 16;

    int2 ri = rowinfo[row];
    int s = ri.x, c = ri.y;

    unsigned int w2 = *(const unsigned int*)(g2 + (size_t)row * 256);
    float base0 = __uint_as_float(w2 << 16) + bias[j0];
    float base1 = __uint_as_float(w2 & 0xffff0000u) + bias[j1];

    float x0 = 0.0f, x1 = 0.0f;
    for (int p0 = 0; p0 < c; p0 += 64) {
        int nav = min(64, c - p0);
        int2 rr = srec[s + p0 + (lane < nav ? lane : 0)];
        int p = 0;
        // 8-wide batches while more than 4 steps remain
        for (; p + 4 < nav; p += 8) {
            int n8 = min(8, nav - p);
            unsigned int w0[8], w1[8];
#pragma unroll
            for (int j = 0; j < 8; ++j) {
                int kk = p + (j < n8 ? j : 0);
                int o0 = __shfl(rr.x, kk);
                int o1 = __shfl(rr.y, kk);
                w0[j] = *(const unsigned int*)(g0 + (size_t)(unsigned)o0);
                w1[j] = *(const unsigned int*)(g1 + (size_t)(unsigned)o1);
            }
#pragma unroll
            for (int j = 0; j < 8; ++j) {
                if (j < n8) {
                    float s0 = __uint_as_float(w0[j] << 16)
                             + __uint_as_float(w1[j] << 16) + base0;
                    float s1 = __uint_as_float(w0[j] & 0xffff0000u)
                             + __uint_as_float(w1[j] & 0xffff0000u) + base1;
                    x0 += gelu_fast(s0);
                    x1 += gelu_fast(s1);
                }
            }
        }
        // 4-wide tail (wave-uniform branch; c is per-row uniform)
        if (p < nav) {
            int n4 = nav - p;   // 1..4
            unsigned int w0[4], w1[4];
#pragma unroll
            for (int j = 0; j < 4; ++j) {
                int kk = p + (j < n4 ? j : 0);
                int o0 = __shfl(rr.x, kk);
                int o1 = __shfl(rr.y, kk);
                w0[j] = *(const unsigned int*)(g0 + (size_t)(unsigned)o0);
                w1[j] = *(const unsigned int*)(g1 + (size_t)(unsigned)o1);
            }
#pragma unroll
            for (int j = 0; j < 4; ++j) {
                if (j < n4) {
                    float s0 = __uint_as_float(w0[j] << 16)
                             + __uint_as_float(w1[j] << 16) + base0;
                    float s1 = __uint_as_float(w0[j] & 0xffff0000u)
                             + __uint_as_float(w1[j] & 0xffff0000u) + base1;
                    x0 += gelu_fast(s0);
                    x1 += gelu_fast(s1);
                }
            }
        }
    }

    float gm0 = gamma[j0], gm1 = gamma[j1];
    float bt0 = beta[j0],  bt1 = beta[j1];

    float inv = 1.0f / fmaxf((float)c, 1.0f);
    float m0 = x0 * inv, m1 = x1 * inv;
    float sm = m0 + m1;
#pragma unroll
    for (int o = 32; o > 0; o >>= 1) sm += __shfl_xor(sm, o);
    float mu = sm * (1.0f / 128.0f);
    float d0 = m0 - mu, d1 = m1 - mu;
    float v = d0 * d0 + d1 * d1;
#pragma unroll
    for (int o = 32; o > 0; o >>= 1) v += __shfl_xor(v, o);
    float rstd = rsqrtf(v * (1.0f / 128.0f) + 1e-5f);
    __builtin_nontemporal_store(d0 * rstd * gm0 + bt0, &out[(size_t)row * 128 + j0]);
    __builtin_nontemporal_store(d1 * rstd * gm1 + bt1, &out[(size_t)row * 128 + j1]);
}

extern "C" void kernel_launch(void* const* d_in, const int* in_sizes, int n_in,
                              void* d_out, int out_size, void* d_ws, size_t ws_size,
                              hipStream_t stream)
{
    const float* fe_f  = (const float*)d_in[0];
    const float* Wg    = (const float*)d_in[1];
    const float* bias  = (const float*)d_in[2];
    const float* gamma = (const float*)d_in[3];
    const float* beta  = (const float*)d_in[4];
    const int*   tri   = (const int*)d_in[5];

    int E = in_sizes[0] / 128;
    int T = in_sizes[5] / 3;

    // ws: G (3*E*128 bf16) | srec (T+8 int2) | wq (96KB) | slot (T i32) |
    //     cnt (E) | excl (E) | partial (1024) | pscan (1024) | rowinfo (E int2)
    unsigned short* G = (unsigned short*)d_ws;
    int2* srec = (int2*)((char*)d_ws + (size_t)3 * E * 256);
    uintx4* wq = (uintx4*)(srec + T + 8);
    int* slot = (int*)(wq + 6144);
    int* cnt  = slot + T;
    int* excl = cnt + E;
    int* partial = excl + E;
    int* pscan = partial + 1024;
    int2* rowinfo = (int2*)(pscan + 1024);

    hipMemsetAsync(cnt, 0, (size_t)E * sizeof(int), stream);

    int total = T + 6144;
    prep<<<(total + 255) / 256, 256, 0, stream>>>(Wg, wq, tri, cnt, slot, T);

    int NB = (E + 1023) / 1024;   // 98 for E=100000 (must be <= 1024)
    scan_blk<<<NB, 1024, 0, stream>>>(cnt, excl, partial, E);
    scan_blk<<<1, 1024, 0, stream>>>(partial, pscan, nullptr, NB);

    scatter<<<(T + 255) / 256, 256, 0, stream>>>(tri, slot, excl, pscan, cnt,
                                                 srec, rowinfo, E, T);

    edge_gemm<<<256, 1024, 0, stream>>>(fe_f, wq, G, E);

    mean_ln<<<(E + 3) / 4, 256, 0, stream>>>(G, rowinfo, srec, bias, gamma, beta,
                                             (float*)d_out, E);
}

// Round 7
// 232.739 us; speedup vs baseline: 1.6536x; 1.0032x over previous
//
#include <hip/hip_runtime.h>
#include <hip/hip_bf16.h>

typedef __attribute__((ext_vector_type(8))) short short8;
typedef __attribute__((ext_vector_type(4))) float floatx4;
typedef __attribute__((ext_vector_type(4))) unsigned int uintx4;

// fast GELU: x * (1 - 1/(exp(2u)+1)), u = 0.79788456*(x + 0.044715 x^3)
__device__ __forceinline__ float gelu_fast(float x)
{
    float u = 0.7978845608f * x * (1.0f + 0.044715f * x * x);
    float e = __builtin_amdgcn_exp2f(2.885390082f * u);   // exp(2u)
    return x - x * __builtin_amdgcn_rcpf(e + 1.0f);
}

// prep: [0,T): count triangles per dst, record slot; [T,T+6144): fragment-
// ordered bf16 W (frag f=ko*8+nt over global ko 0..11, lane l: 8 elems
// W[ko*32+quad*8+j][nt*16+col]).
__global__ __launch_bounds__(256)
void prep(const float* __restrict__ Wg, uintx4* __restrict__ wq,
          const int* __restrict__ tri, int* __restrict__ cnt,
          int* __restrict__ slot, int T)
{
    int g = blockIdx.x * 256 + threadIdx.x;
    if (g < T) {
        int i2 = tri[g * 3 + 2];
        slot[g] = atomicAdd(&cnt[i2], 1);
    } else {
        int i = g - T;
        if (i < 6144) {
            int frag = i >> 6, lane = i & 63;
            int ko = frag >> 3, nt = frag & 7;
            int col = lane & 15, quad = lane >> 4;
            unsigned short tmp[8] __attribute__((aligned(16)));
#pragma unroll
            for (int j = 0; j < 8; ++j) {
                __hip_bfloat16 b =
                    __float2bfloat16(Wg[(ko * 32 + quad * 8 + j) * 128 + nt * 16 + col]);
                tmp[j] = *(unsigned short*)&b;
            }
            wq[i] = *(const uintx4*)tmp;
        }
    }
}

__device__ __forceinline__ int wave_incl_scan(int v, int lane)
{
#pragma unroll
    for (int o = 1; o < 64; o <<= 1) {
        int u = __shfl_up(v, o);
        if (lane >= o) v += u;
    }
    return v;
}

// Block-level exclusive scan of 1024 elements; writes per-element exclusive
// prefix (within block) and block total to partial[] (if non-null).
__global__ __launch_bounds__(1024)
void scan_blk(const int* __restrict__ in, int* __restrict__ outExcl,
              int* __restrict__ partial, int n)
{
    __shared__ int ws[16];
    int t = threadIdx.x;
    int g = blockIdx.x * 1024 + t;
    int lane = t & 63, wv = t >> 6;
    int v = (g < n) ? in[g] : 0;
    int sc = wave_incl_scan(v, lane);
    if (lane == 63) ws[wv] = sc;
    __syncthreads();
    if (wv == 0) {
        int b = (lane < 16) ? ws[lane] : 0;
        int bs = wave_incl_scan(b, lane);
        if (lane < 16) ws[lane] = bs;
    }
    __syncthreads();
    int off = wv ? ws[wv - 1] : 0;
    if (g < n) outExcl[g] = off + sc - v;
    if (partial && t == 0) partial[blockIdx.x] = ws[15];
}

// Scatter triangles into dst-sorted CSR (pure records, pre-scaled byte
// offsets) AND into the 4-slot padded header table srec_pad[dst*4+slot]
// (zero-prefilled). Records are (i<<8) so low bytes are spare: slot0 packs
// min(c,255) in .x and start[7:0] in .y; slot1 packs start[15:8]/.x and
// start[23:16]/.y. One 32B uniform load then yields {c, start, 4 records}.
__global__ __launch_bounds__(256)
void scatter(const int* __restrict__ tri, const int* __restrict__ slot,
             const int* __restrict__ excl, const int* __restrict__ pscan,
             const int* __restrict__ cnt, int2* __restrict__ srec,
             int2* __restrict__ srec_pad, int T)
{
    int g = blockIdx.x * 256 + threadIdx.x;
    if (g >= T) return;
    int i0 = tri[g * 3 + 0];
    int i1 = tri[g * 3 + 1];
    int i2 = tri[g * 3 + 2];
    int sl = slot[g];
    int start = excl[i2] + pscan[i2 >> 10];
    int2 rv = make_int2(i0 << 8, i1 << 8);   // byte offsets into G rows
    srec[start + sl] = rv;
    if (sl < 4) {
        int2 pv = rv;
        if (sl == 0) {
            int c = cnt[i2];
            pv.x |= (c < 255 ? c : 255);
            pv.y |= start & 0xff;
        } else if (sl == 1) {
            pv.x |= (start >> 8) & 0xff;
            pv.y |= (start >> 16) & 0xff;
        }
        srec_pad[(size_t)i2 * 4 + sl] = pv;
    }
}

// One-pass dense GEMM: all 3 W slices resident in 96KB LDS; A tile loaded and
// converted once, used for r=0,1,2. Output bf16, permuted C-layout (row i:
// physical elem col*8+nt = logical col nt*16+col). No barriers in main loop.
__global__ __launch_bounds__(1024, 1)
void edge_gemm(const float* __restrict__ fe_f, const uintx4* __restrict__ wq,
               unsigned short* __restrict__ G, int E)
{
    __shared__ uintx4 ldsW[6144];   // 96 KB: 12 global-ko x 8 nt fragment blocks

    const int tid  = threadIdx.x;
    const int wv   = tid >> 6;
    const int lane = tid & 63;
    const int col  = lane & 15;
    const int quad = lane >> 4;
    const int ntiles = (E + 15) >> 4;

    for (int i = tid; i < 6144; i += 1024) ldsW[i] = wq[i];
    __syncthreads();

#pragma unroll 1
    for (int tile = blockIdx.x * 16 + wv; tile < ntiles; tile += gridDim.x * 16) {
        int row_a = tile * 16 + col;
        if (row_a >= E) row_a = E - 1;
        const float* arow = fe_f + (size_t)row_a * 128 + quad * 8;

        floatx4 f[8];
#pragma unroll
        for (int l = 0; l < 8; ++l)
            f[l] = *(const floatx4*)(arow + (l >> 1) * 32 + (l & 1) * 4);

        short8 a[4];
#pragma unroll
        for (int ko = 0; ko < 4; ++ko) {
            unsigned short tmp[8] __attribute__((aligned(16)));
#pragma unroll
            for (int j = 0; j < 8; ++j) {
                __hip_bfloat16 b = __float2bfloat16(f[ko * 2 + (j >> 2)][j & 3]);
                tmp[j] = *(unsigned short*)&b;
            }
            a[ko] = *(const short8*)tmp;
        }

#pragma unroll 1
        for (int r = 0; r < 3; ++r) {
            floatx4 acc[8];
#pragma unroll
            for (int nt = 0; nt < 8; ++nt) acc[nt] = (floatx4)0.0f;

#pragma unroll
            for (int ko = 0; ko < 4; ++ko) {
#pragma unroll
                for (int nt = 0; nt < 8; ++nt) {
                    short8 bf = *(const short8*)&ldsW[r * 2048 + (ko * 8 + nt) * 64 + lane];
                    acc[nt] = __builtin_amdgcn_mfma_f32_16x16x32_bf16(a[ko], bf, acc[nt], 0, 0, 0);
                }
            }

            unsigned short* Gr = G + (size_t)r * E * 128;
#pragma unroll
            for (int rr = 0; rr < 4; ++rr) {
                int row = tile * 16 + quad * 4 + rr;
                if (row < E) {
                    unsigned short pk[8] __attribute__((aligned(16)));
#pragma unroll
                    for (int nt = 0; nt < 8; ++nt) {
                        __hip_bfloat16 hb = __float2bfloat16(acc[nt][rr]);
                        pk[nt] = *(unsigned short*)&hb;
                    }
                    *(uintx4*)(Gr + (size_t)row * 128 + col * 8) = *(const uintx4*)pk;
                }
            }
        }
    }
}

// Per-edge fused gather + GELU + mean + LayerNorm. Depth-minimal chain:
// depth 1 = one 32B uniform header s_load (c, CSR start, first 4 records) in
// parallel with w2/bias/gamma/beta; depth 2 = row-gathers (saddr+uniform-
// offset form). c<=4 (~63%): exactly 4 steps, done. c in (4,255]: CSR tail
// via clamped uniform s_loads, 4-wide batches (depth 3 for the tail only).
// Sum stays in slot order 0..c-1 (identical numerics to prior rounds).
// Lane (col,q) covers logical cols j0=32q+col, j1=j0+16 (permuted layout).
__global__ __launch_bounds__(256)
void mean_ln(const unsigned short* __restrict__ G, const int* __restrict__ cnt,
             const int2* __restrict__ srec, const uintx4* __restrict__ srec_pad,
             const float* __restrict__ bias, const float* __restrict__ gamma,
             const float* __restrict__ beta, float* __restrict__ out, int E)
{
    int lane = threadIdx.x & 63;
    int row  = blockIdx.x * 4 + (threadIdx.x >> 6);
    if (row >= E) return;
    int urow = __builtin_amdgcn_readfirstlane(row);
    int col = lane & 15, q = lane >> 4;
    int boff = (col << 4) + (q << 2);   // byte offset within 256B row
    const char* g0 = (const char*)G + boff;
    const char* g1 = g0 + (size_t)E * 256;
    const char* g2 = g1 + (size_t)E * 256;
    int j0 = q * 32 + col, j1 = j0 + 16;

    // depth-1: 32B header (uniform -> SGPR) + w2 gather + LN params
    const uintx4* hp = srec_pad + (size_t)urow * 2;
    uintx4 h0 = hp[0];
    uintx4 h1 = hp[1];
    unsigned int w2 = *(const unsigned int*)(g2 + (size_t)urow * 256);
    float bv0 = bias[j0], bv1 = bias[j1];
    float gm0 = gamma[j0], gm1 = gamma[j1];
    float bt0 = beta[j0],  bt1 = beta[j1];

    int c = (int)(h0[0] & 255u);
    if (__builtin_expect(c == 255, 0)) c = cnt[urow];   // ultra-rare fallback

    const unsigned int M = 0xffffff00u;
    unsigned int a0[4] = { h0[0] & M, h0[2] & M, h1[0] & M, h1[2] & M };
    unsigned int a1[4] = { h0[1] & M, h0[3] & M, h1[1] & M, h1[3] & M };

    float base0 = __uint_as_float(w2 << 16) + bv0;
    float base1 = __uint_as_float(w2 & 0xffff0000u) + bv1;

    float x0 = 0.0f, x1 = 0.0f;

    if (c <= 4) {
        // fast path: 4 steps, all gathers at depth 2
        unsigned int w0[4], w1[4];
#pragma unroll
        for (int j = 0; j < 4; ++j) {
            w0[j] = *(const unsigned int*)(g0 + (size_t)a0[j]);
            w1[j] = *(const unsigned int*)(g1 + (size_t)a1[j]);
        }
#pragma unroll
        for (int j = 0; j < 4; ++j) {
            bool ok = j < c;
            float s0 = __uint_as_float(w0[j] << 16)
                     + __uint_as_float(w1[j] << 16) + base0;
            float s1 = __uint_as_float(w0[j] & 0xffff0000u)
                     + __uint_as_float(w1[j] & 0xffff0000u) + base1;
            x0 += ok ? gelu_fast(s0) : 0.0f;
            x1 += ok ? gelu_fast(s1) : 0.0f;
        }
    } else {
        int start = (int)((h0[1] & 255u) | ((h0[2] & 255u) << 8)
                        | ((h0[3] & 255u) << 16));
        start = __builtin_amdgcn_readfirstlane(start);

        // first 4 records (header), all valid since c > 4
        unsigned int w0[4], w1[4];
#pragma unroll
        for (int j = 0; j < 4; ++j) {
            w0[j] = *(const unsigned int*)(g0 + (size_t)a0[j]);
            w1[j] = *(const unsigned int*)(g1 + (size_t)a1[j]);
        }
#pragma unroll
        for (int j = 0; j < 4; ++j) {
            float s0 = __uint_as_float(w0[j] << 16)
                     + __uint_as_float(w1[j] << 16) + base0;
            float s1 = __uint_as_float(w0[j] & 0xffff0000u)
                     + __uint_as_float(w1[j] & 0xffff0000u) + base1;
            x0 += gelu_fast(s0);
            x1 += gelu_fast(s1);
        }

        // CSR tail, 4-wide batches; clamped uniform record loads (no pad
        // needed: clamped index <= c-1 stays inside this row's CSR range)
        for (int p = 4; p < c; p += 4) {
            int2 cr[4];
#pragma unroll
            for (int j = 0; j < 4; ++j) {
                int idx = p + j;
                if (idx > c - 1) idx = c - 1;
                cr[j] = srec[start + idx];
            }
            unsigned int u0[4], u1[4];
#pragma unroll
            for (int j = 0; j < 4; ++j) {
                u0[j] = *(const unsigned int*)(g0 + (size_t)(unsigned)cr[j].x);
                u1[j] = *(const unsigned int*)(g1 + (size_t)(unsigned)cr[j].y);
            }
#pragma unroll
            for (int j = 0; j < 4; ++j) {
                bool ok = (p + j) < c;
                float s0 = __uint_as_float(u0[j] << 16)
                         + __uint_as_float(u1[j] << 16) + base0;
                float s1 = __uint_as_float(u0[j] & 0xffff0000u)
                         + __uint_as_float(u1[j] & 0xffff0000u) + base1;
                x0 += ok ? gelu_fast(s0) : 0.0f;
                x1 += ok ? gelu_fast(s1) : 0.0f;
            }
        }
    }

    float inv = 1.0f / fmaxf((float)c, 1.0f);
    float m0 = x0 * inv, m1 = x1 * inv;
    float sm = m0 + m1;
#pragma unroll
    for (int o = 32; o > 0; o >>= 1) sm += __shfl_xor(sm, o);
    float mu = sm * (1.0f / 128.0f);
    float d0 = m0 - mu, d1 = m1 - mu;
    float v = d0 * d0 + d1 * d1;
#pragma unroll
    for (int o = 32; o > 0; o >>= 1) v += __shfl_xor(v, o);
    float rstd = rsqrtf(v * (1.0f / 128.0f) + 1e-5f);
    __builtin_nontemporal_store(d0 * rstd * gm0 + bt0, &out[(size_t)urow * 128 + j0]);
    __builtin_nontemporal_store(d1 * rstd * gm1 + bt1, &out[(size_t)urow * 128 + j1]);
}

extern "C" void kernel_launch(void* const* d_in, const int* in_sizes, int n_in,
                              void* d_out, int out_size, void* d_ws, size_t ws_size,
                              hipStream_t stream)
{
    const float* fe_f  = (const float*)d_in[0];
    const float* Wg    = (const float*)d_in[1];
    const float* bias  = (const float*)d_in[2];
    const float* gamma = (const float*)d_in[3];
    const float* beta  = (const float*)d_in[4];
    const int*   tri   = (const int*)d_in[5];

    int E = in_sizes[0] / 128;
    int T = in_sizes[5] / 3;

    // ws (total == proven 83.7MB layout):
    //   [G: 3*E*256 B]  -- written only by edge_gemm; its front doubles as
    //       pre-gemm scratch: slot (T i32) | excl (E i32) | partial | pscan
    //   [srec: T int2]  [srec_pad: E*4 int2]  [cnt: E i32]  [wq: 96KB]
    char* base = (char*)d_ws;
    unsigned short* G = (unsigned short*)base;
    int* slot    = (int*)base;                         // dies before edge_gemm
    int* excl    = (int*)(base + (size_t)T * 4);
    int* partial = (int*)(base + (size_t)T * 4 + (size_t)E * 4);
    int* pscan   = partial + 1024;

    char* p = base + (size_t)3 * E * 256;
    int2* srec = (int2*)p;                 p += (size_t)T * 8;
    int2* srec_pad = (int2*)p;             p += (size_t)E * 32;
    int* cnt = (int*)p;                    p += (size_t)E * 4;
    uintx4* wq = (uintx4*)p;

    // zero srec_pad + cnt (contiguous)
    (void)hipMemsetAsync(srec_pad, 0, (size_t)E * 32 + (size_t)E * 4, stream);

    int total = T + 6144;
    prep<<<(total + 255) / 256, 256, 0, stream>>>(Wg, wq, tri, cnt, slot, T);

    int NB = (E + 1023) / 1024;   // 98 for E=100000 (must be <= 1024)
    scan_blk<<<NB, 1024, 0, stream>>>(cnt, excl, partial, E);
    scan_blk<<<1, 1024, 0, stream>>>(partial, pscan, nullptr, NB);

    scatter<<<(T + 255) / 256, 256, 0, stream>>>(tri, slot, excl, pscan, cnt,
                                                 srec, srec_pad, T);

    edge_gemm<<<256, 1024, 0, stream>>>(fe_f, wq, G, E);

    mean_ln<<<(E + 3) / 4, 256, 0, stream>>>(G, cnt, srec,
                                             (const uintx4*)srec_pad,
                                             bias, gamma, beta, (float*)d_out, E);
}